// Round 18
// baseline (224.055 us; speedup 1.0000x reference)
//
#include <hip/hip_runtime.h>
#include <hip/hip_bf16.h>

typedef __attribute__((ext_vector_type(8))) _Float16       h8;
typedef __attribute__((ext_vector_type(2))) _Float16       h2;
typedef __attribute__((ext_vector_type(8))) unsigned short u16x8;
typedef __attribute__((ext_vector_type(4))) float          f4;
typedef __attribute__((ext_vector_type(4))) unsigned int   u32x4;
typedef __attribute__((ext_vector_type(2))) unsigned int   u32x2;

__device__ __forceinline__ h2 bch2(unsigned int w) { return __builtin_bit_cast(h2, w); }
__device__ __forceinline__ unsigned int pkrtz(float a, float b) {
    auto r = __builtin_amdgcn_cvt_pkrtz(a, b);
    return __builtin_bit_cast(unsigned int, r);
}
__device__ __forceinline__ void gload_lds16(const void* g, void* l) {
    __builtin_amdgcn_global_load_lds(
        (const __attribute__((address_space(1))) unsigned int*)g,
        (__attribute__((address_space(3))) unsigned int*)l, 16, 0, 0);
}

// Convert the 4 weight matrices (each 512x512 fp32) to f16, concatenated.
__global__ __launch_bounds__(256) void cvt_w4(const float* __restrict__ a,
                                              const float* __restrict__ b,
                                              const float* __restrict__ c,
                                              const float* __restrict__ d,
                                              unsigned short* __restrict__ o) {
    const int i   = (blockIdx.x * 256 + threadIdx.x) * 8;
    const int seg = i >> 18;
    const int off = i & 262143;
    const float* s = (seg == 0) ? a : (seg == 1) ? b : (seg == 2) ? c : d;
    f4 x0 = *(const f4*)(s + off);
    f4 x1 = *(const f4*)(s + off + 4);
    u32x4 t;
    t[0] = pkrtz(x0[0], x0[1]);
    t[1] = pkrtz(x0[2], x0[3]);
    t[2] = pkrtz(x1[0], x1[1]);
    t[3] = pkrtz(x1[2], x1[3]);
    *(u32x4*)(o + i) = t;
}

// Projection GEMM, round-18: BM=128 x BN=256, 512-thread blocks.
// Intensity 85 FLOP/staged-byte (vs 51 at BM=64) via f16 A in LDS
// (reg-staged fp32->pkrtz->ds_write, 80B padded rows); W via proven
// XOR-swizzled gload_lds dbuf. 53 KB static LDS + 64-VGPR acc ->
// 2 blocks/CU = 16 waves/CU (2x occupancy of the old proj3).
// Pipeline per iter: issue Aload(t+2) | barrier | MFMA(t) | barrier |
// vmcnt(0) | write A(t+2)+issue W(t+2) into drained buf | lgkmcnt(0).
__global__ __launch_bounds__(512, 4) void gemm_p2(const float* __restrict__ q,
                                                  const float* __restrict__ k,
                                                  const float* __restrict__ v,
                                                  const unsigned short* __restrict__ Wb,
                                                  const float* __restrict__ bq,
                                                  const float* __restrict__ bk,
                                                  const float* __restrict__ bv,
                                                  unsigned short* __restrict__ qh,
                                                  unsigned short* __restrict__ kh,
                                                  unsigned short* __restrict__ vh,
                                                  float scale) {
    constexpr int KD = 512, BK = 32, NT = KD / BK;   // 16 K-tiles
    constexpr int APAD = 40;                         // shorts per A row (80 B)
    constexpr int ASZ  = 128 * APAD * 2;             // 10240 B
    constexpr int WSZ  = 256 * BK * 2;               // 16384 B
    constexpr int STRIDE = ASZ + WSZ;                // 26624 B
    __shared__ unsigned char lds[2 * STRIDE];        // 53248 B -> 2 blocks/CU

    const int z = blockIdx.z;
    const float* Af           = (z == 0) ? q  : (z == 1) ? k  : v;
    const float* bias         = (z == 0) ? bq : (z == 1) ? bk : bv;
    unsigned short* Out       = (z == 0) ? qh : (z == 1) ? kh : vh;
    const unsigned short* W   = Wb + (size_t)z * 262144;
    const float fscale        = (z == 0) ? scale : 1.0f;

    const int tid  = threadIdx.x;                    // 0..511
    const int lane = tid & 63;
    const int w    = tid >> 6;                       // 0..7
    const int wm   = w >> 2;                         // 0..1  (M half)
    const int wn   = w & 3;                          // 0..3  (N quarter)
    const int n0   = blockIdx.x * 256;
    const size_t m0 = (size_t)blockIdx.y * 128;

    const int fr = lane & 15;                        // frag row/col
    const int j4 = lane >> 4;                        // k-slot
    const int arow = tid >> 2;                       // A stage row 0..127
    const int acol = (tid & 3) * 8;                  // A stage col 0/8/16/24

    f4 acc[4][4];
#pragma unroll
    for (int i = 0; i < 4; ++i)
#pragma unroll
        for (int j = 0; j < 4; ++j) acc[i][j] = (f4)(0.0f);

    auto wissue = [&](int t) {                       // W tile t -> buf t&1 (2 instr)
        unsigned char* base = lds + (t & 1) * STRIDE + ASZ;
        const int kt = t * BK;
#pragma unroll
        for (int i = 0; i < 2; ++i) {
            const int f = i * 512 + tid;
            const int l = f ^ ((f >> 3) & 7);
            gload_lds16(W + (size_t)(n0 + (l >> 2)) * KD + kt + (l & 3) * 8,
                        base + f * 16);
        }
    };
    auto aload = [&](int t, f4& r0, f4& r1) {        // 2 instr
        const float* p = Af + (m0 + arow) * KD + t * BK + acol;
        r0 = *(const f4*)p;
        r1 = *(const f4*)(p + 4);
    };
    auto awrite = [&](int t, const f4& r0, const f4& r1) {
        u32x4 t4;
        t4[0] = pkrtz(r0[0], r0[1]);
        t4[1] = pkrtz(r0[2], r0[3]);
        t4[2] = pkrtz(r1[0], r1[1]);
        t4[3] = pkrtz(r1[2], r1[3]);
        *(u32x4*)(lds + (t & 1) * STRIDE + arow * (APAD * 2) + acol * 2) = t4;
    };

    // prologue: A(0),A(1) staged; W(0),W(1) issued; W(0) retired.
    {
        f4 a0, a1;
        aload(0, a0, a1); awrite(0, a0, a1);
        aload(1, a0, a1); awrite(1, a0, a1);
    }
    wissue(0);
    wissue(1);
    asm volatile("s_waitcnt vmcnt(2)" ::: "memory");   // W(0) done; W(1) in flight
    asm volatile("s_waitcnt lgkmcnt(0)" ::: "memory"); // A writes done

    for (int t = 0; t < NT; ++t) {
        unsigned char* base = lds + (t & 1) * STRIDE;
        f4 r0, r1;
        if (t + 2 < NT) aload(t + 2, r0, r1);          // +2 vmcnt
        __builtin_amdgcn_s_barrier();                  // A(t),W(t) visible
        __builtin_amdgcn_sched_barrier(0);

        h8 af[4];
#pragma unroll
        for (int mi = 0; mi < 4; ++mi)
            af[mi] = *(const h8*)(base + (wm * 64 + mi * 16 + fr) * (APAD * 2)
                                  + j4 * 16);
#pragma unroll
        for (int ni = 0; ni < 4; ++ni) {
            const int row = wn * 64 + ni * 16 + fr;    // 0..255
            const int L = (row << 2) | j4;
            const int P = L ^ ((L >> 3) & 7);
            const h8 wf = *(const h8*)(base + ASZ + (P << 4));
#pragma unroll
            for (int mi = 0; mi < 4; ++mi)
                acc[mi][ni] = __builtin_amdgcn_mfma_f32_16x16x32_f16(
                    af[mi], wf, acc[mi][ni], 0, 0, 0);
        }

        __builtin_amdgcn_sched_barrier(0);
        __builtin_amdgcn_s_barrier();                  // all reads of buf t done
        __builtin_amdgcn_sched_barrier(0);
        asm volatile("s_waitcnt vmcnt(0)" ::: "memory"); // retire W(t+1)+Aregs
        if (t + 2 < NT) {
            awrite(t + 2, r0, r1);                     // into buf t&1 (drained)
            wissue(t + 2);                             // W(t+2) in flight
        }
        asm volatile("s_waitcnt lgkmcnt(0)" ::: "memory"); // A writes before next barrier
        __builtin_amdgcn_sched_barrier(0);
    }

    const int rq = (lane >> 4) << 2;
#pragma unroll
    for (int ni = 0; ni < 4; ++ni) {
        const int   col = n0 + wn * 64 + ni * 16 + fr;
        const float bv  = bias[col];
#pragma unroll
        for (int mi = 0; mi < 4; ++mi) {
            const size_t rbase = m0 + wm * 64 + mi * 16 + rq;
#pragma unroll
            for (int r = 0; r < 4; ++r) {
                const float val = (acc[mi][ni][r] + bv) * fscale;
                const _Float16 hv = (_Float16)val;
                Out[(rbase + r) * KD + col] = __builtin_bit_cast(unsigned short, hv);
            }
        }
    }
}

// R11 gemm_body (kept for outk: measured 11.6 us): full-N, dbuf LDS, BK=32,
// counted vmcnt, vmcnt(0) tail, both-sides XOR swizzle, f16 MFMA.
template <bool AF32, bool OF32>
__device__ __forceinline__ void gemm_body(const void* __restrict__ Ap,
                                          const unsigned short* __restrict__ Wb,
                                          const float* __restrict__ bias,
                                          void* __restrict__ Outp,
                                          float scale,
                                          unsigned char* lds) {
    constexpr int KD = 512, BK = 32, NT = KD / BK;
    constexpr int ASZ = AF32 ? 64 * BK * 4 : 64 * BK * 2;
    constexpr int WSZ = 512 * BK * 2;
    constexpr int STRIDE = ASZ + WSZ;

    const int tid  = threadIdx.x;
    const int lane = tid & 63;
    const int w    = tid >> 6;
    const size_t m0 = (size_t)blockIdx.x * 64;

    const float*          Af = (const float*)Ap;
    const unsigned short* Ab = (const unsigned short*)Ap;

    const int fr = lane & 15;
    const int j4 = lane >> 4;

    f4 acc[4][8];
#pragma unroll
    for (int i = 0; i < 4; ++i)
#pragma unroll
        for (int j = 0; j < 8; ++j) acc[i][j] = (f4)(0.0f);

    auto stage = [&](int t, int buf) {
        const int kt = t * BK;
        unsigned char* base = lds + buf * STRIDE;
        if constexpr (AF32) {
#pragma unroll
            for (int i = 0; i < 2; ++i) {
                const int f = i * 256 + tid;
                const int row = f >> 3, p = f & 7;
                const int s = p ^ (row & 7);
                gload_lds16(Af + (m0 + row) * KD + kt + s * 4, base + f * 16);
            }
        } else {
            const int f = tid;
            const int l = f ^ ((f >> 3) & 7);
            gload_lds16(Ab + (m0 + (l >> 2)) * KD + kt + (l & 3) * 8, base + f * 16);
        }
#pragma unroll
        for (int i = 0; i < 8; ++i) {
            const int f = i * 256 + tid;
            const int l = f ^ ((f >> 3) & 7);
            gload_lds16(Wb + (size_t)(l >> 2) * KD + kt + (l & 3) * 8,
                        base + ASZ + f * 16);
        }
    };

    stage(0, 0);
    stage(1, 1);

    for (int t = 0; t < NT; ++t) {
        const int buf = t & 1;
        unsigned char* base = lds + buf * STRIDE;
        if (t + 1 < NT) {
            if constexpr (AF32) asm volatile("s_waitcnt vmcnt(10)" ::: "memory");
            else                asm volatile("s_waitcnt vmcnt(9)"  ::: "memory");
        } else {
            asm volatile("s_waitcnt vmcnt(0)" ::: "memory");
        }
        __builtin_amdgcn_s_barrier();
        __builtin_amdgcn_sched_barrier(0);

        h8 af[4];
#pragma unroll
        for (int mi = 0; mi < 4; ++mi) {
            const int row = mi * 16 + fr;
            if constexpr (AF32) {
                const int r7 = row & 7;
                const int s0 = j4 * 2;
                f4 x0 = *(const f4*)(base + row * 128 + ((s0 ^ r7) << 4));
                f4 x1 = *(const f4*)(base + row * 128 + (((s0 + 1) ^ r7) << 4));
                u32x4 t4;
                t4[0] = pkrtz(x0[0], x0[1]);
                t4[1] = pkrtz(x0[2], x0[3]);
                t4[2] = pkrtz(x1[0], x1[1]);
                t4[3] = pkrtz(x1[2], x1[3]);
                af[mi] = __builtin_bit_cast(h8, t4);
            } else {
                const int L = (row << 2) | j4;
                const int P = L ^ ((L >> 3) & 7);
                af[mi] = *(const h8*)(base + (P << 4));
            }
        }
#pragma unroll
        for (int ni = 0; ni < 8; ++ni) {
            const int nrow = w * 128 + ni * 16 + fr;
            const int L = (nrow << 2) | j4;
            const int P = L ^ ((L >> 3) & 7);
            const h8 bf = *(const h8*)(base + ASZ + (P << 4));
#pragma unroll
            for (int mi = 0; mi < 4; ++mi)
                acc[mi][ni] = __builtin_amdgcn_mfma_f32_16x16x32_f16(
                    af[mi], bf, acc[mi][ni], 0, 0, 0);
        }

        __builtin_amdgcn_sched_barrier(0);
        __builtin_amdgcn_s_barrier();
        __builtin_amdgcn_sched_barrier(0);
        if (t + 2 < NT) stage(t + 2, buf);
    }

    const int rq = (lane >> 4) << 2;
#pragma unroll
    for (int ni = 0; ni < 8; ++ni) {
        const int   col = w * 128 + ni * 16 + fr;
        const float bv  = bias[col];
#pragma unroll
        for (int mi = 0; mi < 4; ++mi) {
            const size_t rbase = m0 + mi * 16 + rq;
#pragma unroll
            for (int r = 0; r < 4; ++r) {
                const float val = (acc[mi][ni][r] + bv) * scale;
                if constexpr (OF32) {
                    ((float*)Outp)[(rbase + r) * KD + col] = val;
                } else {
                    const _Float16 hv = (_Float16)val;
                    ((unsigned short*)Outp)[(rbase + r) * KD + col] =
                        __builtin_bit_cast(unsigned short, hv);
                }
            }
        }
    }
}

__global__ __launch_bounds__(256, 2) void gemm_outk(const unsigned short* __restrict__ Xb,
                                                    const unsigned short* __restrict__ Wb,
                                                    const float* __restrict__ bias,
                                                    float* __restrict__ Out) {
    extern __shared__ unsigned char lds[];
    gemm_body<false, true>(Xb, Wb, bias, Out, 1.0f, lds);
}

// LDS-tiled NAT, f16 dot2, LDK=40 b128 reads (measured best: 74 us).
__global__ __launch_bounds__(256, 4) void natt(const unsigned short* __restrict__ qh,
                                               const unsigned short* __restrict__ kh,
                                               const unsigned short* __restrict__ vh,
                                               const float* __restrict__ rpb,
                                               unsigned short* __restrict__ xout) {
    constexpr int LDK = 40;
    __shared__ unsigned short KV[484][LDK];
    __shared__ float Rs[169];

    const int tid = threadIdx.x;
    const int h   = blockIdx.z & 15;
    const int b   = blockIdx.z >> 4;
    const int x0  = blockIdx.x * 16;
    const int y0  = blockIdx.y * 16;
    const int ux0 = min(max(x0 - 3, 0), 106);
    const int uy0 = min(max(y0 - 3, 0), 106);
    const int tx  = tid & 15;
    const int ty  = tid >> 4;
    const int x   = x0 + tx;
    const int y   = y0 + ty;

    if (tid < 169) Rs[tid] = rpb[h * 169 + tid];

    const long imgbase = (long)b * 128 * 128;

#pragma unroll 2
    for (int kk = tid; kk < 484; kk += 256) {
        const int ky = uy0 + kk / 22;
        const int kx = ux0 + kk % 22;
        const unsigned short* src = kh + (imgbase + ky * 128 + kx) * 512 + h * 32;
#pragma unroll
        for (int j = 0; j < 4; ++j)
            *(u16x8*)&KV[kk][j * 8] = *(const u16x8*)(src + j * 8);
    }

    const long pix = imgbase + y * 128 + x;
    const unsigned short* qp = qh + pix * 512 + h * 32;
    h2 qv[16];
    {
        const u32x4* q32 = (const u32x4*)qp;
#pragma unroll
        for (int j = 0; j < 4; ++j) {
            const u32x4 wv = q32[j];
#pragma unroll
            for (int e = 0; e < 4; ++e) qv[j * 4 + e] = bch2(wv[e]);
        }
    }

    const int myy = min(max(y - 3, 0), 121) - uy0;
    const int myx = min(max(x - 3, 0), 121) - ux0;
    const int pbY = (y < 3) ? (6 - y) : ((y >= 125) ? (127 - y) : 3);
    const int pbX = (x < 3) ? (6 - x) : ((x >= 125) ? (127 - x) : 3);

    __syncthreads();

    float logit[49];
#pragma unroll
    for (int a = 0; a < 7; ++a) {
        const int rowk = (myy + a) * 22 + myx;
#pragma unroll
        for (int c = 0; c < 7; ++c) {
            const u32x4* kp = (const u32x4*)&KV[rowk + c][0];
            float s0 = 0.f, s1 = 0.f;
#pragma unroll
            for (int j = 0; j < 4; ++j) {
                const u32x4 wv = kp[j];
                s0 = __builtin_amdgcn_fdot2(qv[4 * j + 0], bch2(wv[0]), s0, false);
                s1 = __builtin_amdgcn_fdot2(qv[4 * j + 1], bch2(wv[1]), s1, false);
                s0 = __builtin_amdgcn_fdot2(qv[4 * j + 2], bch2(wv[2]), s0, false);
                s1 = __builtin_amdgcn_fdot2(qv[4 * j + 3], bch2(wv[3]), s1, false);
            }
            logit[a * 7 + c] = s0 + s1 + Rs[(pbY + a) * 13 + pbX + c];
        }
    }

    float m = logit[0];
#pragma unroll
    for (int i = 1; i < 49; ++i) m = fmaxf(m, logit[i]);
    float sum = 0.f;
#pragma unroll
    for (int i = 0; i < 49; ++i) {
        float p = exp2f((logit[i] - m) * 1.4426950408889634f);
        logit[i] = p;
        sum += p;
    }
    const float rinv = 1.f / sum;
#pragma unroll
    for (int i = 0; i < 49; ++i) logit[i] *= rinv;

    __syncthreads();

#pragma unroll 2
    for (int kk = tid; kk < 484; kk += 256) {
        const int ky = uy0 + kk / 22;
        const int kx = ux0 + kk % 22;
        const unsigned short* src = vh + (imgbase + ky * 128 + kx) * 512 + h * 32;
#pragma unroll
        for (int j = 0; j < 4; ++j)
            *(u16x8*)&KV[kk][j * 8] = *(const u16x8*)(src + j * 8);
    }
    __syncthreads();

    float acc[32];
#pragma unroll
    for (int d = 0; d < 32; ++d) acc[d] = 0.f;
#pragma unroll
    for (int a = 0; a < 7; ++a) {
        const int rowk = (myy + a) * 22 + myx;
#pragma unroll
        for (int c = 0; c < 7; ++c) {
            const u32x4* vp = (const u32x4*)&KV[rowk + c][0];
            const float wgt = logit[a * 7 + c];
#pragma unroll
            for (int j = 0; j < 4; ++j) {
                const u32x4 wv = vp[j];
#pragma unroll
                for (int e = 0; e < 4; ++e) {
                    const h2 hv = bch2(wv[e]);
                    acc[8 * j + 2 * e]     = fmaf((float)hv[0], wgt, acc[8 * j + 2 * e]);
                    acc[8 * j + 2 * e + 1] = fmaf((float)hv[1], wgt, acc[8 * j + 2 * e + 1]);
                }
            }
        }
    }

    unsigned short* op = xout + pix * 512 + h * 32;
#pragma unroll
    for (int j = 0; j < 4; ++j) {
        u32x2 p;
        p[0] = pkrtz(acc[8 * j + 0], acc[8 * j + 1]);
        p[1] = pkrtz(acc[8 * j + 2], acc[8 * j + 3]);
        u32x2 p2;
        p2[0] = pkrtz(acc[8 * j + 4], acc[8 * j + 5]);
        p2[1] = pkrtz(acc[8 * j + 6], acc[8 * j + 7]);
        *(u32x2*)(op + j * 8)     = p;
        *(u32x2*)(op + j * 8 + 4) = p2;
    }
}

extern "C" void kernel_launch(void* const* d_in, const int* in_sizes, int n_in,
                              void* d_out, int out_size, void* d_ws, size_t ws_size,
                              hipStream_t stream) {
    const float* q   = (const float*)d_in[0];
    const float* k   = (const float*)d_in[1];
    const float* v   = (const float*)d_in[2];
    const float* wq  = (const float*)d_in[3];
    const float* bq  = (const float*)d_in[4];
    const float* wk  = (const float*)d_in[5];
    const float* bk  = (const float*)d_in[6];
    const float* wv  = (const float*)d_in[7];
    const float* bv  = (const float*)d_in[8];
    const float* rpb = (const float*)d_in[9];
    const float* wo  = (const float*)d_in[10];
    const float* bo  = (const float*)d_in[11];

    const long P = 2l * 128 * 128;  // 32768 pixels
    unsigned short* qh = (unsigned short*)d_ws;
    unsigned short* kh = qh + P * 512;
    unsigned short* vh = kh + P * 512;
    unsigned short* xb = vh + P * 512;
    unsigned short* Wb = xb + P * 512;   // 4 x 512 x 512 f16 (2 MB)

    const float scale = 0.17677669529663687f;  // 32^-0.5
    const size_t smemB = 2 * (64 * 32 * 2 + 512 * 32 * 2);  // 73728

    cvt_w4<<<512, 256, 0, stream>>>(wq, wk, wv, wo, Wb);

    gemm_p2<<<dim3(2, 256, 3), 512, 0, stream>>>(
        q, k, v, Wb, bq, bk, bv, qh, kh, vh, scale);

    natt<<<dim3(8, 8, 32), 256, 0, stream>>>(qh, kh, vh, rpb, xb);

    gemm_outk<<<512, 256, smemB, stream>>>(xb, Wb + 786432, bo, (float*)d_out);
}

// Round 19
// 222.119 us; speedup vs baseline: 1.0087x; 1.0087x over previous
//
#include <hip/hip_runtime.h>
#include <hip/hip_bf16.h>

typedef __attribute__((ext_vector_type(8))) _Float16       h8;
typedef __attribute__((ext_vector_type(2))) _Float16       h2;
typedef __attribute__((ext_vector_type(8))) unsigned short u16x8;
typedef __attribute__((ext_vector_type(4))) float          f4;
typedef __attribute__((ext_vector_type(4))) unsigned int   u32x4;
typedef __attribute__((ext_vector_type(2))) unsigned int   u32x2;

__device__ __forceinline__ h2 bch2(unsigned int w) { return __builtin_bit_cast(h2, w); }
__device__ __forceinline__ unsigned int pkrtz(float a, float b) {
    auto r = __builtin_amdgcn_cvt_pkrtz(a, b);
    return __builtin_bit_cast(unsigned int, r);
}
__device__ __forceinline__ void gload_lds16(const void* g, void* l) {
    __builtin_amdgcn_global_load_lds(
        (const __attribute__((address_space(1))) unsigned int*)g,
        (__attribute__((address_space(3))) unsigned int*)l, 16, 0, 0);
}

// Convert the 4 weight matrices (each 512x512 fp32) to f16, concatenated.
__global__ __launch_bounds__(256) void cvt_w4(const float* __restrict__ a,
                                              const float* __restrict__ b,
                                              const float* __restrict__ c,
                                              const float* __restrict__ d,
                                              unsigned short* __restrict__ o) {
    const int i   = (blockIdx.x * 256 + threadIdx.x) * 8;
    const int seg = i >> 18;
    const int off = i & 262143;
    const float* s = (seg == 0) ? a : (seg == 1) ? b : (seg == 2) ? c : d;
    f4 x0 = *(const f4*)(s + off);
    f4 x1 = *(const f4*)(s + off + 4);
    u32x4 t;
    t[0] = pkrtz(x0[0], x0[1]);
    t[1] = pkrtz(x0[2], x0[3]);
    t[2] = pkrtz(x1[0], x1[1]);
    t[3] = pkrtz(x1[2], x1[3]);
    *(u32x4*)(o + i) = t;
}

// R11 gemm_body: full-N blocks, dbuf LDS, BK=32, counted vmcnt, vmcnt(0)
// tail, both-sides XOR swizzle, f16 MFMA; fp32 A staged raw + pkrtz at read.
// Best-measured GEMM config across 12 structural variants (R0-R18):
// the pipeline is bound by the effective HBM mixed-stream rate (~2.2-2.7
// TB/s demonstrated on this working set), not by schedule/occupancy.
template <bool AF32, bool OF32>
__device__ __forceinline__ void gemm_body(const void* __restrict__ Ap,
                                          const unsigned short* __restrict__ Wb,
                                          const float* __restrict__ bias,
                                          void* __restrict__ Outp,
                                          float scale,
                                          unsigned char* lds) {
    constexpr int KD = 512, BK = 32, NT = KD / BK;            // 16 K-tiles
    constexpr int ASZ = AF32 ? 64 * BK * 4 : 64 * BK * 2;     // 8 KB / 4 KB
    constexpr int WSZ = 512 * BK * 2;                          // 32 KB
    constexpr int STRIDE = ASZ + WSZ;

    const int tid  = threadIdx.x;
    const int lane = tid & 63;
    const int w    = tid >> 6;            // wave -> cols [w*128, w*128+128)
    const size_t m0 = (size_t)blockIdx.x * 64;

    const float*          Af = (const float*)Ap;
    const unsigned short* Ab = (const unsigned short*)Ap;

    const int fr = lane & 15;             // frag row (A) / col (B/D)
    const int j4 = lane >> 4;             // k-slot 0..3

    f4 acc[4][8];
#pragma unroll
    for (int i = 0; i < 4; ++i)
#pragma unroll
        for (int j = 0; j < 8; ++j) acc[i][j] = (f4)(0.0f);

    auto stage = [&](int t, int buf) {
        const int kt = t * BK;
        unsigned char* base = lds + buf * STRIDE;
        if constexpr (AF32) {
#pragma unroll
            for (int i = 0; i < 2; ++i) {
                const int f = i * 256 + tid;
                const int row = f >> 3, p = f & 7;
                const int s = p ^ (row & 7);
                gload_lds16(Af + (m0 + row) * KD + kt + s * 4, base + f * 16);
            }
        } else {
            const int f = tid;
            const int l = f ^ ((f >> 3) & 7);
            gload_lds16(Ab + (m0 + (l >> 2)) * KD + kt + (l & 3) * 8, base + f * 16);
        }
#pragma unroll
        for (int i = 0; i < 8; ++i) {
            const int f = i * 256 + tid;
            const int l = f ^ ((f >> 3) & 7);
            gload_lds16(Wb + (size_t)(l >> 2) * KD + kt + (l & 3) * 8,
                        base + ASZ + f * 16);
        }
    };

    stage(0, 0);
    stage(1, 1);

    for (int t = 0; t < NT; ++t) {
        const int buf = t & 1;
        unsigned char* base = lds + buf * STRIDE;
        if (t + 1 < NT) {
            if constexpr (AF32) asm volatile("s_waitcnt vmcnt(10)" ::: "memory");
            else                asm volatile("s_waitcnt vmcnt(9)"  ::: "memory");
        } else {
            asm volatile("s_waitcnt vmcnt(0)" ::: "memory");
        }
        __builtin_amdgcn_s_barrier();
        __builtin_amdgcn_sched_barrier(0);

        h8 af[4];
#pragma unroll
        for (int mi = 0; mi < 4; ++mi) {
            const int row = mi * 16 + fr;
            if constexpr (AF32) {
                const int r7 = row & 7;
                const int s0 = j4 * 2;
                f4 x0 = *(const f4*)(base + row * 128 + ((s0 ^ r7) << 4));
                f4 x1 = *(const f4*)(base + row * 128 + (((s0 + 1) ^ r7) << 4));
                u32x4 t4;
                t4[0] = pkrtz(x0[0], x0[1]);
                t4[1] = pkrtz(x0[2], x0[3]);
                t4[2] = pkrtz(x1[0], x1[1]);
                t4[3] = pkrtz(x1[2], x1[3]);
                af[mi] = __builtin_bit_cast(h8, t4);
            } else {
                const int L = (row << 2) | j4;
                const int P = L ^ ((L >> 3) & 7);
                af[mi] = *(const h8*)(base + (P << 4));
            }
        }
#pragma unroll
        for (int ni = 0; ni < 8; ++ni) {
            const int nrow = w * 128 + ni * 16 + fr;
            const int L = (nrow << 2) | j4;
            const int P = L ^ ((L >> 3) & 7);
            const h8 bf = *(const h8*)(base + ASZ + (P << 4));
#pragma unroll
            for (int mi = 0; mi < 4; ++mi)
                acc[mi][ni] = __builtin_amdgcn_mfma_f32_16x16x32_f16(
                    af[mi], bf, acc[mi][ni], 0, 0, 0);
        }

        __builtin_amdgcn_sched_barrier(0);
        __builtin_amdgcn_s_barrier();
        __builtin_amdgcn_sched_barrier(0);
        if (t + 2 < NT) stage(t + 2, buf);
    }

    const int rq = (lane >> 4) << 2;
#pragma unroll
    for (int ni = 0; ni < 8; ++ni) {
        const int   col = w * 128 + ni * 16 + fr;
        const float bv  = bias[col];
#pragma unroll
        for (int mi = 0; mi < 4; ++mi) {
            const size_t rbase = m0 + mi * 16 + rq;
#pragma unroll
            for (int r = 0; r < 4; ++r) {
                const float val = (acc[mi][ni][r] + bv) * scale;
                if constexpr (OF32) {
                    ((float*)Outp)[(rbase + r) * KD + col] = val;
                } else {
                    const _Float16 hv = (_Float16)val;
                    ((unsigned short*)Outp)[(rbase + r) * KD + col] =
                        __builtin_bit_cast(unsigned short, hv);
                }
            }
        }
    }
}

// 3 projections in one launch (measured-best: 130 us for all three).
__global__ __launch_bounds__(256, 2) void gemm_proj3(const float* __restrict__ q,
                                                     const float* __restrict__ k,
                                                     const float* __restrict__ v,
                                                     const unsigned short* __restrict__ Wb,
                                                     const float* __restrict__ bq,
                                                     const float* __restrict__ bk,
                                                     const float* __restrict__ bv,
                                                     unsigned short* __restrict__ qh,
                                                     unsigned short* __restrict__ kh,
                                                     unsigned short* __restrict__ vh,
                                                     float scale) {
    extern __shared__ unsigned char lds[];
    const int by = blockIdx.y;
    const float*          A  = (by == 0) ? q  : (by == 1) ? k  : v;
    const float*          bi = (by == 0) ? bq : (by == 1) ? bk : bv;
    unsigned short*       O  = (by == 0) ? qh : (by == 1) ? kh : vh;
    gemm_body<true, false>(A, Wb + (size_t)by * 262144, bi, O,
                           (by == 0) ? scale : 1.0f, lds);
}

__global__ __launch_bounds__(256, 2) void gemm_outk(const unsigned short* __restrict__ Xb,
                                                    const unsigned short* __restrict__ Wb,
                                                    const float* __restrict__ bias,
                                                    float* __restrict__ Out) {
    extern __shared__ unsigned char lds[];
    gemm_body<false, true>(Xb, Wb, bias, Out, 1.0f, lds);
}

// LDS-tiled NAT, f16 dot2, LDK=40 b128 reads (measured best: 74 us,
// VGPR 52, occupancy 35%). Layout-fix attempts (runtime-XOR swizzle,
// LDK=44+b64) both regressed: occupancy + LDS instruction count are the
// binding resources here.
__global__ __launch_bounds__(256, 4) void natt(const unsigned short* __restrict__ qh,
                                               const unsigned short* __restrict__ kh,
                                               const unsigned short* __restrict__ vh,
                                               const float* __restrict__ rpb,
                                               unsigned short* __restrict__ xout) {
    constexpr int LDK = 40;
    __shared__ unsigned short KV[484][LDK];
    __shared__ float Rs[169];

    const int tid = threadIdx.x;
    const int h   = blockIdx.z & 15;
    const int b   = blockIdx.z >> 4;
    const int x0  = blockIdx.x * 16;
    const int y0  = blockIdx.y * 16;
    const int ux0 = min(max(x0 - 3, 0), 106);
    const int uy0 = min(max(y0 - 3, 0), 106);
    const int tx  = tid & 15;
    const int ty  = tid >> 4;
    const int x   = x0 + tx;
    const int y   = y0 + ty;

    if (tid < 169) Rs[tid] = rpb[h * 169 + tid];

    const long imgbase = (long)b * 128 * 128;

#pragma unroll 2
    for (int kk = tid; kk < 484; kk += 256) {
        const int ky = uy0 + kk / 22;
        const int kx = ux0 + kk % 22;
        const unsigned short* src = kh + (imgbase + ky * 128 + kx) * 512 + h * 32;
#pragma unroll
        for (int j = 0; j < 4; ++j)
            *(u16x8*)&KV[kk][j * 8] = *(const u16x8*)(src + j * 8);
    }

    const long pix = imgbase + y * 128 + x;
    const unsigned short* qp = qh + pix * 512 + h * 32;
    h2 qv[16];
    {
        const u32x4* q32 = (const u32x4*)qp;
#pragma unroll
        for (int j = 0; j < 4; ++j) {
            const u32x4 wv = q32[j];
#pragma unroll
            for (int e = 0; e < 4; ++e) qv[j * 4 + e] = bch2(wv[e]);
        }
    }

    const int myy = min(max(y - 3, 0), 121) - uy0;
    const int myx = min(max(x - 3, 0), 121) - ux0;
    const int pbY = (y < 3) ? (6 - y) : ((y >= 125) ? (127 - y) : 3);
    const int pbX = (x < 3) ? (6 - x) : ((x >= 125) ? (127 - x) : 3);

    __syncthreads();

    float logit[49];
#pragma unroll
    for (int a = 0; a < 7; ++a) {
        const int rowk = (myy + a) * 22 + myx;
#pragma unroll
        for (int c = 0; c < 7; ++c) {
            const u32x4* kp = (const u32x4*)&KV[rowk + c][0];
            float s0 = 0.f, s1 = 0.f;
#pragma unroll
            for (int j = 0; j < 4; ++j) {
                const u32x4 wv = kp[j];
                s0 = __builtin_amdgcn_fdot2(qv[4 * j + 0], bch2(wv[0]), s0, false);
                s1 = __builtin_amdgcn_fdot2(qv[4 * j + 1], bch2(wv[1]), s1, false);
                s0 = __builtin_amdgcn_fdot2(qv[4 * j + 2], bch2(wv[2]), s0, false);
                s1 = __builtin_amdgcn_fdot2(qv[4 * j + 3], bch2(wv[3]), s1, false);
            }
            logit[a * 7 + c] = s0 + s1 + Rs[(pbY + a) * 13 + pbX + c];
        }
    }

    float m = logit[0];
#pragma unroll
    for (int i = 1; i < 49; ++i) m = fmaxf(m, logit[i]);
    float sum = 0.f;
#pragma unroll
    for (int i = 0; i < 49; ++i) {
        float p = exp2f((logit[i] - m) * 1.4426950408889634f);
        logit[i] = p;
        sum += p;
    }
    const float rinv = 1.f / sum;
#pragma unroll
    for (int i = 0; i < 49; ++i) logit[i] *= rinv;

    __syncthreads();

#pragma unroll 2
    for (int kk = tid; kk < 484; kk += 256) {
        const int ky = uy0 + kk / 22;
        const int kx = ux0 + kk % 22;
        const unsigned short* src = vh + (imgbase + ky * 128 + kx) * 512 + h * 32;
#pragma unroll
        for (int j = 0; j < 4; ++j)
            *(u16x8*)&KV[kk][j * 8] = *(const u16x8*)(src + j * 8);
    }
    __syncthreads();

    float acc[32];
#pragma unroll
    for (int d = 0; d < 32; ++d) acc[d] = 0.f;
#pragma unroll
    for (int a = 0; a < 7; ++a) {
        const int rowk = (myy + a) * 22 + myx;
#pragma unroll
        for (int c = 0; c < 7; ++c) {
            const u32x4* vp = (const u32x4*)&KV[rowk + c][0];
            const float wgt = logit[a * 7 + c];
#pragma unroll
            for (int j = 0; j < 4; ++j) {
                const u32x4 wv = vp[j];
#pragma unroll
                for (int e = 0; e < 4; ++e) {
                    const h2 hv = bch2(wv[e]);
                    acc[8 * j + 2 * e]     = fmaf((float)hv[0], wgt, acc[8 * j + 2 * e]);
                    acc[8 * j + 2 * e + 1] = fmaf((float)hv[1], wgt, acc[8 * j + 2 * e + 1]);
                }
            }
        }
    }

    unsigned short* op = xout + pix * 512 + h * 32;
#pragma unroll
    for (int j = 0; j < 4; ++j) {
        u32x2 p;
        p[0] = pkrtz(acc[8 * j + 0], acc[8 * j + 1]);
        p[1] = pkrtz(acc[8 * j + 2], acc[8 * j + 3]);
        u32x2 p2;
        p2[0] = pkrtz(acc[8 * j + 4], acc[8 * j + 5]);
        p2[1] = pkrtz(acc[8 * j + 6], acc[8 * j + 7]);
        *(u32x2*)(op + j * 8)     = p;
        *(u32x2*)(op + j * 8 + 4) = p2;
    }
}

extern "C" void kernel_launch(void* const* d_in, const int* in_sizes, int n_in,
                              void* d_out, int out_size, void* d_ws, size_t ws_size,
                              hipStream_t stream) {
    const float* q   = (const float*)d_in[0];
    const float* k   = (const float*)d_in[1];
    const float* v   = (const float*)d_in[2];
    const float* wq  = (const float*)d_in[3];
    const float* bq  = (const float*)d_in[4];
    const float* wk  = (const float*)d_in[5];
    const float* bk  = (const float*)d_in[6];
    const float* wv  = (const float*)d_in[7];
    const float* bv  = (const float*)d_in[8];
    const float* rpb = (const float*)d_in[9];
    const float* wo  = (const float*)d_in[10];
    const float* bo  = (const float*)d_in[11];

    const long P = 2l * 128 * 128;  // 32768 pixels
    unsigned short* qh = (unsigned short*)d_ws;
    unsigned short* kh = qh + P * 512;
    unsigned short* vh = kh + P * 512;
    unsigned short* xb = vh + P * 512;
    unsigned short* Wb = xb + P * 512;   // 4 x 512 x 512 f16 (2 MB)

    const float scale = 0.17677669529663687f;  // 32^-0.5
    const size_t smemF = 2 * (64 * 32 * 4 + 512 * 32 * 2);  // 81920
    const size_t smemB = 2 * (64 * 32 * 2 + 512 * 32 * 2);  // 73728

    cvt_w4<<<512, 256, 0, stream>>>(wq, wk, wv, wo, Wb);

    gemm_proj3<<<dim3(512, 3, 1), 256, smemF, stream>>>(
        q, k, v, Wb, bq, bk, bv, qh, kh, vh, scale);

    natt<<<dim3(8, 8, 32), 256, 0, stream>>>(qh, kh, vh, rpb, xb);

    gemm_outk<<<512, 256, smemB, stream>>>(xb, Wb + 786432, bo, (float*)d_out);
}